// Round 13
// baseline (74.798 us; speedup 1.0000x reference)
//
#include <hip/hip_runtime.h>
#include <math.h>

#define N_ATOMS 512
#define N_MOL   16
#define HIDDEN  128
#define FILTERS 128
#define NUM_RBF 50
#define CUTOFF  10.0f
#define N_LAYERS 3

#define KB4    4096                  // nearest-neighbor bins over [0,10]
#define NB4    (KB4 + 1)             // rows 0..4096 (row 4096 = zeros via env)
#define TBPL   129                   // table blocks per layer (129*32 >= 4097 bins)
#define TBLK   (N_LAYERS * TBPL)     // 387 table blocks
#define EMBB   16                    // emb blocks, 32 atoms each
#define NBLK   (N_ATOMS / 2)         // fused-layer grid: 256 blocks (one per CU)
#define PI_F   3.14159265358979f
#define DINV   409.6f                // KB4 / CUTOFF
#define DSTEP  (CUTOFF / (float)KB4)

__device__ __forceinline__ unsigned short f2bf(float v) {
    unsigned u = __float_as_uint(v);
    u += 0x7fffu + ((u >> 16) & 1u);     // round-to-nearest-even
    return (unsigned short)(u >> 16);
}

// ====== front: filter tables as per-block fused GEMM (32 bins/block) ∥ embedding+xj0 ======
// (unchanged from R12 — proven; also zeroes molsum/done for the fused-layer kernel)
__global__ void __launch_bounds__(256) k_front(
        const int* __restrict__ an, const float* __restrict__ emb,
        const float* __restrict__ d1w, const float* __restrict__ d1b,
        const float* __restrict__ fw1, const float* __restrict__ fb1,
        const float* __restrict__ fw2, const float* __restrict__ fb2,
        float* __restrict__ x, unsigned short* __restrict__ xj,
        unsigned short* __restrict__ tab, float* __restrict__ molsum,
        int* __restrict__ done) {
    __shared__ float s_rbf[32][NUM_RBF];
    __shared__ __align__(16) float s_H[32][132];
    __shared__ __align__(16) float s_row[32][HIDDEN];
    __shared__ int   s_an[32];
    int bid = blockIdx.x, t = threadIdx.x;

    if (bid == 0) {
        for (int idx = t; idx < N_MOL * HIDDEN; idx += 256) molsum[idx] = 0.f;
        if (t < 4) done[t] = 0;
    }

    int cq = t & 31, ag = t >> 5;

    if (bid < TBLK) {
        int l = bid / TBPL, bx = bid - l * TBPL;
        int bin0 = bx * 32;
        const float* w1g = fw1 + (size_t)l * NUM_RBF * FILTERS;
        const float* w2g = fw2 + (size_t)l * FILTERS * FILTERS;
        for (int idx = t; idx < 32 * NUM_RBF; idx += 256) {
            int lb = idx / NUM_RBF, r = idx - lb * NUM_RBF;
            float dd = (bin0 + lb) * DSTEP;
            float cr = r * (CUTOFF / (float)(NUM_RBF - 1));
            float xx = dd - cr;
            s_rbf[lb][r] = __expf(-xx * xx * 12.5f);
        }
        __syncthreads();
        {
            float h[4][4];
            float4 bv = *(const float4*)(fb1 + (size_t)l * FILTERS + 4 * cq);
            float bva[4] = { bv.x, bv.y, bv.z, bv.w };
            #pragma unroll
            for (int aa = 0; aa < 4; aa++)
                #pragma unroll
                for (int cc = 0; cc < 4; cc++) h[aa][cc] = bva[cc];
            #pragma unroll 2
            for (int r = 0; r < NUM_RBF; r++) {
                float4 w = *(const float4*)(w1g + (size_t)r * FILTERS + 4 * cq);
                float wa[4] = { w.x, w.y, w.z, w.w };
                #pragma unroll
                for (int aa = 0; aa < 4; aa++) {
                    float rb = s_rbf[ag * 4 + aa][r];
                    #pragma unroll
                    for (int cc = 0; cc < 4; cc++) h[aa][cc] = fmaf(rb, wa[cc], h[aa][cc]);
                }
            }
            __syncthreads();
            #pragma unroll
            for (int aa = 0; aa < 4; aa++) {
                float4 sv;
                sv.x = h[aa][0] / (1.f + __expf(-h[aa][0]));
                sv.y = h[aa][1] / (1.f + __expf(-h[aa][1]));
                sv.z = h[aa][2] / (1.f + __expf(-h[aa][2]));
                sv.w = h[aa][3] / (1.f + __expf(-h[aa][3]));
                *(float4*)(&s_H[ag * 4 + aa][4 * cq]) = sv;
            }
        }
        __syncthreads();
        float o[4][4];
        float4 b2v = *(const float4*)(fb2 + (size_t)l * FILTERS + 4 * cq);
        float b2a[4] = { b2v.x, b2v.y, b2v.z, b2v.w };
        #pragma unroll
        for (int aa = 0; aa < 4; aa++)
            #pragma unroll
            for (int cc = 0; cc < 4; cc++) o[aa][cc] = b2a[cc];
        #pragma unroll 4
        for (int hh = 0; hh < FILTERS; hh += 2) {
            float4 wA = *(const float4*)(w2g + (size_t)hh * FILTERS + 4 * cq);
            float4 wB = *(const float4*)(w2g + (size_t)(hh + 1) * FILTERS + 4 * cq);
            float wa[4] = { wA.x, wA.y, wA.z, wA.w };
            float wb[4] = { wB.x, wB.y, wB.z, wB.w };
            #pragma unroll
            for (int aa = 0; aa < 4; aa++) {
                float2 hp = *(const float2*)(&s_H[ag * 4 + aa][hh]);
                #pragma unroll
                for (int cc = 0; cc < 4; cc++) {
                    o[aa][cc] = fmaf(hp.x, wa[cc], o[aa][cc]);
                    o[aa][cc] = fmaf(hp.y, wb[cc], o[aa][cc]);
                }
            }
        }
        size_t base = (size_t)l * NB4 * FILTERS;
        #pragma unroll
        for (int aa = 0; aa < 4; aa++) {
            int bin = bin0 + ag * 4 + aa;
            if (bin <= KB4) {
                float dd = bin * DSTEP;
                float env = (bin >= KB4) ? 0.f : 0.5f * (__cosf(dd * (PI_F / CUTOFF)) + 1.f);
                #pragma unroll
                for (int cp = 0; cp < 2; cp++) {
                    unsigned int pk = (unsigned)f2bf(o[aa][2 * cp] * env) |
                                      ((unsigned)f2bf(o[aa][2 * cp + 1] * env) << 16);
                    *(unsigned int*)(tab + base + (size_t)bin * FILTERS + 4 * cq + 2 * cp) = pk;
                }
            }
        }
    } else {
        int eb = bid - TBLK;
        int i0 = eb * 32;
        if (t < 32) s_an[t] = an[i0 + t];
        __syncthreads();
        for (int idx = t; idx < 32 * HIDDEN; idx += 256) {
            int a = idx >> 7, c = idx & 127;
            float v = emb[(size_t)s_an[a] * HIDDEN + c];
            s_row[a][c] = v;
            x[(size_t)(i0 + a) * HIDDEN + c] = v;
        }
        __syncthreads();
        float o[4][4];
        float4 bv = *(const float4*)(d1b + 4 * cq);
        float bva[4] = { bv.x, bv.y, bv.z, bv.w };
        #pragma unroll
        for (int aa = 0; aa < 4; aa++)
            #pragma unroll
            for (int cc = 0; cc < 4; cc++) o[aa][cc] = bva[cc];
        #pragma unroll 4
        for (int h = 0; h < HIDDEN; h += 2) {
            float4 wA = *(const float4*)(d1w + (size_t)h * FILTERS + 4 * cq);
            float4 wB = *(const float4*)(d1w + (size_t)(h + 1) * FILTERS + 4 * cq);
            float wa[4] = { wA.x, wA.y, wA.z, wA.w };
            float wb[4] = { wB.x, wB.y, wB.z, wB.w };
            #pragma unroll
            for (int aa = 0; aa < 4; aa++) {
                float2 hp = *(const float2*)(&s_row[ag * 4 + aa][h]);
                #pragma unroll
                for (int cc = 0; cc < 4; cc++) {
                    o[aa][cc] = fmaf(hp.x, wa[cc], o[aa][cc]);
                    o[aa][cc] = fmaf(hp.y, wb[cc], o[aa][cc]);
                }
            }
        }
        #pragma unroll
        for (int aa = 0; aa < 4; aa++) {
            int i = i0 + ag * 4 + aa;
            #pragma unroll
            for (int cp = 0; cp < 2; cp++) {
                unsigned int pk = (unsigned)f2bf(o[aa][2 * cp]) |
                                  ((unsigned)f2bf(o[aa][2 * cp + 1]) << 16);
                *(unsigned int*)(xj + (size_t)i * FILTERS + 4 * cq + 2 * cp) = pk;
            }
        }
    }
}

// ============ fused 3-layer + pool persistent kernel (256 blocks, 2 atoms each) ============
// Cross-layer xj handoff uses device-coherent relaxed atomics (AGENT scope) + done-counter
// spin — the fence-free protocol proven by the R11/R12 pool tail. No threadfence, no cg.
__global__ void __launch_bounds__(512) k_layers(const float* __restrict__ pos,
        const unsigned int* __restrict__ tabu, const unsigned int* __restrict__ xj0,
        unsigned int* __restrict__ xj1, unsigned int* __restrict__ xj2,
        const float* __restrict__ x,
        const float* __restrict__ d2w, const float* __restrict__ d2b,
        const float* __restrict__ d1w, const float* __restrict__ d1b,
        const int* __restrict__ batch, float* __restrict__ molsum, int* __restrict__ done,
        const float* __restrict__ ow1, const float* __restrict__ ob1,
        const float* __restrict__ ow2, const float* __restrict__ ob2,
        float* __restrict__ out) {
    int bid = blockIdx.x, t = threadIdx.x;
    int j0a = 2 * bid, j1a = j0a + 1;
    int wv = t >> 6, e = t & 63;
    __shared__ unsigned int s_bin[N_ATOMS];
    __shared__ float s_part[2][8][FILTERS];
    __shared__ float s_red[4][FILTERS];
    __shared__ float s_agg[2][FILTERS];
    __shared__ float s_xn[2][HIDDEN];
    __shared__ int   s_cnt;
    {   // distances once (reused by all 3 layers)
        float px = pos[3*t], py = pos[3*t+1], pz = pos[3*t+2];
        float ax = pos[3*j0a], ay = pos[3*j0a+1], az = pos[3*j0a+2];
        float bx = pos[3*j1a], by = pos[3*j1a+1], bz = pos[3*j1a+2];
        float d0 = sqrtf((px-ax)*(px-ax) + (py-ay)*(py-ay) + (pz-az)*(pz-az));
        float d1 = sqrtf((px-bx)*(px-bx) + (py-by)*(py-by) + (pz-bz)*(pz-bz));
        unsigned int b0 = (t == j0a || d0 >= CUTOFF) ? KB4 : (unsigned)(int)fmaf(d0, DINV, 0.5f);
        unsigned int b1 = (t == j1a || d1 >= CUTOFF) ? KB4 : (unsigned)(int)fmaf(d1, DINV, 0.5f);
        if (b0 > KB4) b0 = KB4;
        if (b1 > KB4) b1 = KB4;
        s_bin[t] = b0 | (b1 << 16);
    }
    int c = t & 127, seg = t >> 7, jj = seg >> 1, sub = seg & 1;
    int jmy = jj ? j1a : j0a;
    float xcur = (sub == 0) ? x[(size_t)jmy * HIDDEN + c] : 0.f;   // x row lives in-register
    __syncthreads();

    for (int l = 0; l < N_LAYERS; l++) {
        const unsigned int* tabl = tabu + (size_t)l * NB4 * 64;
        const unsigned int* xin  = (l == 0) ? xj0 : (l == 1) ? xj1 : xj2;
        // ---- aggregation: wave wv covers i in [wv*64,+64) for both j's ----
        float a0e = 0.f, a0o = 0.f, a1e = 0.f, a1o = 0.f;
        int i0 = wv * 64;
        if (l == 0) {
            for (int ii = 0; ii < 64; ii += 4) {
                #pragma unroll
                for (int r = 0; r < 4; r++) {
                    unsigned int pk = s_bin[i0 + ii + r];
                    unsigned int bb0 = pk & 0xffffu, bb1 = pk >> 16;
                    unsigned int xu = xin[(size_t)(i0 + ii + r) * 64 + e];
                    unsigned int f0 = tabl[(size_t)bb0 * 64 + e];
                    unsigned int f1 = tabl[(size_t)bb1 * 64 + e];
                    float xe = __uint_as_float(xu << 16), xo = __uint_as_float(xu & 0xffff0000u);
                    float p0e = __uint_as_float(f0 << 16), p0o = __uint_as_float(f0 & 0xffff0000u);
                    float p1e = __uint_as_float(f1 << 16), p1o = __uint_as_float(f1 & 0xffff0000u);
                    a0e = fmaf(xe, p0e, a0e);  a0o = fmaf(xo, p0o, a0o);
                    a1e = fmaf(xe, p1e, a1e);  a1o = fmaf(xo, p1o, a1o);
                }
            }
        } else {
            for (int ii = 0; ii < 64; ii += 4) {
                #pragma unroll
                for (int r = 0; r < 4; r++) {
                    unsigned int pk = s_bin[i0 + ii + r];
                    unsigned int bb0 = pk & 0xffffu, bb1 = pk >> 16;
                    unsigned int xu = __hip_atomic_load(&xin[(size_t)(i0 + ii + r) * 64 + e],
                                        __ATOMIC_RELAXED, __HIP_MEMORY_SCOPE_AGENT);
                    unsigned int f0 = tabl[(size_t)bb0 * 64 + e];
                    unsigned int f1 = tabl[(size_t)bb1 * 64 + e];
                    float xe = __uint_as_float(xu << 16), xo = __uint_as_float(xu & 0xffff0000u);
                    float p0e = __uint_as_float(f0 << 16), p0o = __uint_as_float(f0 & 0xffff0000u);
                    float p1e = __uint_as_float(f1 << 16), p1o = __uint_as_float(f1 & 0xffff0000u);
                    a0e = fmaf(xe, p0e, a0e);  a0o = fmaf(xo, p0o, a0o);
                    a1e = fmaf(xe, p1e, a1e);  a1o = fmaf(xo, p1o, a1o);
                }
            }
        }
        s_part[0][wv][2*e] = a0e;  s_part[0][wv][2*e+1] = a0o;
        s_part[1][wv][2*e] = a1e;  s_part[1][wv][2*e+1] = a1o;
        __syncthreads();
        if (t < 256) {
            int pj = t >> 7, cc = t & 127;
            float s = 0.f;
            #pragma unroll
            for (int w8 = 0; w8 < 8; w8++) s += s_part[pj][w8][cc];
            s_agg[pj][cc] = s;
        }
        __syncthreads();
        // ---- x update ----
        const float* w2 = d2w + (size_t)l * FILTERS * HIDDEN;
        const float* b2 = d2b + (size_t)l * HIDDEN;
        float v = 0.f;
        #pragma unroll 8
        for (int ff = sub * 64; ff < sub * 64 + 64; ff++)
            v = fmaf(s_agg[jj][ff], w2[(size_t)ff * HIDDEN + c], v);
        s_red[seg][c] = v;
        __syncthreads();
        if (sub == 0) {
            xcur = xcur + b2[c] + s_red[jj*2][c] + s_red[jj*2+1][c];
            s_xn[jj][c] = xcur;
        }
        __syncthreads();
        if (l < N_LAYERS - 1) {
            // ---- next xj = x @ d1w[l+1] + d1b[l+1] ----
            const float* w1n = d1w + (size_t)(l + 1) * HIDDEN * FILTERS;
            const float* b1n = d1b + (size_t)(l + 1) * FILTERS;
            float a2 = 0.f;
            #pragma unroll 8
            for (int hh = sub * 64; hh < sub * 64 + 64; hh++)
                a2 = fmaf(s_xn[jj][hh], w1n[(size_t)hh * FILTERS + c], a2);
            s_red[seg][c] = a2;
            __syncthreads();
            if (sub == 0) s_agg[jj][c] = b1n[c] + s_red[jj*2][c] + s_red[jj*2+1][c];
            __syncthreads();
            unsigned int* xout = (l == 0) ? xj1 : xj2;
            if (t < 128) {
                int row = t >> 6, ee = t & 63;
                unsigned int pk = (unsigned)f2bf(s_agg[row][2*ee]) |
                                  ((unsigned)f2bf(s_agg[row][2*ee+1]) << 16);
                __hip_atomic_store(&xout[(size_t)(j0a + row) * 64 + ee], pk,
                                   __ATOMIC_RELAXED, __HIP_MEMORY_SCOPE_AGENT);
            }
            __syncthreads();                 // vmcnt drained: coherent stores ack'd
            if (t == 0) {
                atomicAdd(&done[l], 1);
                while (__hip_atomic_load(&done[l], __ATOMIC_RELAXED,
                                         __HIP_MEMORY_SCOPE_AGENT) < NBLK)
                    __builtin_amdgcn_s_sleep(16);
            }
            __syncthreads();
        }
    }
    // ---- pool: accumulate, count, 16 spinner blocks finish ----
    if (sub == 0) atomicAdd(&molsum[(size_t)batch[jmy] * HIDDEN + c], xcur);
    __syncthreads();
    if (t == 0) atomicAdd(&done[2], 1);
    if (bid < N_MOL) {
        int m = bid;
        if (t == 0) {
            while (__hip_atomic_load(&done[2], __ATOMIC_RELAXED,
                                     __HIP_MEMORY_SCOPE_AGENT) < NBLK)
                __builtin_amdgcn_s_sleep(16);
            s_cnt = 0;
        }
        __syncthreads();
        atomicAdd(&s_cnt, (batch[t] == m) ? 1 : 0);
        __syncthreads();
        int cnt = s_cnt;
        if (t < HIDDEN)
            s_xn[0][t] = atomicAdd(&molsum[(size_t)m * HIDDEN + t], 0.f)
                       / (float)(cnt > 0 ? cnt : 1);
        __syncthreads();
        int o = t & 63, sl = t >> 6;
        float a = 0.f;
        #pragma unroll 8
        for (int h = sl * 16; h < sl * 16 + 16; h++)
            a = fmaf(s_xn[0][h], ow1[h * 64 + o], a);
        float* sr = (float*)s_part;
        sr[sl * 64 + o] = a;
        __syncthreads();
        if (t < 64) {
            float vv = ob1[t];
            #pragma unroll
            for (int s8 = 0; s8 < 8; s8++) vv += sr[s8 * 64 + t];
            float hh = vv / (1.f + __expf(-vv));
            float d2 = hh * ow2[t];
            for (int off = 32; off > 0; off >>= 1) d2 += __shfl_down(d2, off, 64);
            if (t == 0) out[m] = d2 + ob2[0];
        }
    }
}

extern "C" void kernel_launch(void* const* d_in, const int* in_sizes, int n_in,
                              void* d_out, int out_size, void* d_ws, size_t ws_size,
                              hipStream_t stream) {
    const int*   an    = (const int*)  d_in[0];
    const float* pos   = (const float*)d_in[1];
    const int*   batch = (const int*)  d_in[2];
    const float* emb   = (const float*)d_in[3];
    const float* fw1   = (const float*)d_in[4];
    const float* fb1   = (const float*)d_in[5];
    const float* fw2   = (const float*)d_in[6];
    const float* fb2   = (const float*)d_in[7];
    const float* d1w   = (const float*)d_in[8];
    const float* d1b   = (const float*)d_in[9];
    const float* d2w   = (const float*)d_in[10];
    const float* d2b   = (const float*)d_in[11];
    const float* ow1   = (const float*)d_in[12];
    const float* ob1   = (const float*)d_in[13];
    const float* ow2   = (const float*)d_in[14];
    const float* ob2   = (const float*)d_in[15];
    float* out = (float*)d_out;

    float*          x    = (float*)d_ws;                               // 256 KB
    unsigned short* xj0  = (unsigned short*)(x + N_ATOMS * HIDDEN);    // 128 KB
    unsigned int*   xj1  = (unsigned int*)(xj0 + (size_t)N_ATOMS * FILTERS);   // 128 KB
    unsigned int*   xj2  = xj1 + (size_t)N_ATOMS * 64;                 // 128 KB
    unsigned short* tab  = (unsigned short*)(xj2 + (size_t)N_ATOMS * 64);      // 3.07 MB
    float*          mols = (float*)(tab + (size_t)N_LAYERS * NB4 * FILTERS);
    int*            done = (int*)(mols + N_MOL * HIDDEN);

    k_front<<<TBLK + EMBB, 256, 0, stream>>>(
        an, emb, d1w, d1b, fw1, fb1, fw2, fb2, x, xj0, tab, mols, done);

    k_layers<<<NBLK, 512, 0, stream>>>(pos, (const unsigned int*)tab,
        (const unsigned int*)xj0, xj1, xj2, x,
        d2w, d2b, d1w, d1b, batch, mols, done, ow1, ob1, ow2, ob2, out);
}

// Round 14
// 74.186 us; speedup vs baseline: 1.0082x; 1.0082x over previous
//
#include <hip/hip_runtime.h>
#include <math.h>

#define N_ATOMS 512
#define N_MOL   16
#define HIDDEN  128
#define FILTERS 128
#define NUM_RBF 50
#define CUTOFF  10.0f
#define N_LAYERS 3

#define KB4    4096                  // nearest-neighbor bins over [0,10]
#define NB4    (KB4 + 1)             // rows 0..4096 (row 4096 = zeros via env)
#define TBPL   129                   // table blocks per layer (129*32 >= 4097 bins)
#define TBLK   (N_LAYERS * TBPL)     // 387 table blocks
#define EMBB   16                    // emb blocks, 32 atoms each
#define NBLK   (N_ATOMS / 2)         // fused-layer grid: 256 blocks (one per CU)
#define PI_F   3.14159265358979f
#define DINV   409.6f                // KB4 / CUTOFF
#define DSTEP  (CUTOFF / (float)KB4)

__device__ __forceinline__ unsigned short f2bf(float v) {
    unsigned u = __float_as_uint(v);
    u += 0x7fffu + ((u >> 16) & 1u);     // round-to-nearest-even
    return (unsigned short)(u >> 16);
}

// ====== front: filter tables as per-block fused GEMM (32 bins/block) ∥ embedding+xj0 ======
__global__ void __launch_bounds__(256) k_front(
        const int* __restrict__ an, const float* __restrict__ emb,
        const float* __restrict__ d1w, const float* __restrict__ d1b,
        const float* __restrict__ fw1, const float* __restrict__ fb1,
        const float* __restrict__ fw2, const float* __restrict__ fb2,
        float* __restrict__ x, unsigned short* __restrict__ xj,
        unsigned short* __restrict__ tab, float* __restrict__ molsum,
        int* __restrict__ done) {
    __shared__ float s_rbf[32][NUM_RBF];
    __shared__ __align__(16) float s_H[32][132];
    __shared__ __align__(16) float s_row[32][HIDDEN];
    __shared__ int   s_an[32];
    int bid = blockIdx.x, t = threadIdx.x;

    if (bid == 0) {
        for (int idx = t; idx < N_MOL * HIDDEN; idx += 256) molsum[idx] = 0.f;
        if (t < 4) done[t] = 0;
    }

    int cq = t & 31, ag = t >> 5;

    if (bid < TBLK) {
        int l = bid / TBPL, bx = bid - l * TBPL;
        int bin0 = bx * 32;
        const float* w1g = fw1 + (size_t)l * NUM_RBF * FILTERS;
        const float* w2g = fw2 + (size_t)l * FILTERS * FILTERS;
        for (int idx = t; idx < 32 * NUM_RBF; idx += 256) {
            int lb = idx / NUM_RBF, r = idx - lb * NUM_RBF;
            float dd = (bin0 + lb) * DSTEP;
            float cr = r * (CUTOFF / (float)(NUM_RBF - 1));
            float xx = dd - cr;
            s_rbf[lb][r] = __expf(-xx * xx * 12.5f);
        }
        __syncthreads();
        {
            float h[4][4];
            float4 bv = *(const float4*)(fb1 + (size_t)l * FILTERS + 4 * cq);
            float bva[4] = { bv.x, bv.y, bv.z, bv.w };
            #pragma unroll
            for (int aa = 0; aa < 4; aa++)
                #pragma unroll
                for (int cc = 0; cc < 4; cc++) h[aa][cc] = bva[cc];
            #pragma unroll 2
            for (int r = 0; r < NUM_RBF; r++) {
                float4 w = *(const float4*)(w1g + (size_t)r * FILTERS + 4 * cq);
                float wa[4] = { w.x, w.y, w.z, w.w };
                #pragma unroll
                for (int aa = 0; aa < 4; aa++) {
                    float rb = s_rbf[ag * 4 + aa][r];
                    #pragma unroll
                    for (int cc = 0; cc < 4; cc++) h[aa][cc] = fmaf(rb, wa[cc], h[aa][cc]);
                }
            }
            __syncthreads();
            #pragma unroll
            for (int aa = 0; aa < 4; aa++) {
                float4 sv;
                sv.x = h[aa][0] / (1.f + __expf(-h[aa][0]));
                sv.y = h[aa][1] / (1.f + __expf(-h[aa][1]));
                sv.z = h[aa][2] / (1.f + __expf(-h[aa][2]));
                sv.w = h[aa][3] / (1.f + __expf(-h[aa][3]));
                *(float4*)(&s_H[ag * 4 + aa][4 * cq]) = sv;
            }
        }
        __syncthreads();
        float o[4][4];
        float4 b2v = *(const float4*)(fb2 + (size_t)l * FILTERS + 4 * cq);
        float b2a[4] = { b2v.x, b2v.y, b2v.z, b2v.w };
        #pragma unroll
        for (int aa = 0; aa < 4; aa++)
            #pragma unroll
            for (int cc = 0; cc < 4; cc++) o[aa][cc] = b2a[cc];
        #pragma unroll 4
        for (int hh = 0; hh < FILTERS; hh += 2) {
            float4 wA = *(const float4*)(w2g + (size_t)hh * FILTERS + 4 * cq);
            float4 wB = *(const float4*)(w2g + (size_t)(hh + 1) * FILTERS + 4 * cq);
            float wa[4] = { wA.x, wA.y, wA.z, wA.w };
            float wb[4] = { wB.x, wB.y, wB.z, wB.w };
            #pragma unroll
            for (int aa = 0; aa < 4; aa++) {
                float2 hp = *(const float2*)(&s_H[ag * 4 + aa][hh]);
                #pragma unroll
                for (int cc = 0; cc < 4; cc++) {
                    o[aa][cc] = fmaf(hp.x, wa[cc], o[aa][cc]);
                    o[aa][cc] = fmaf(hp.y, wb[cc], o[aa][cc]);
                }
            }
        }
        size_t base = (size_t)l * NB4 * FILTERS;
        #pragma unroll
        for (int aa = 0; aa < 4; aa++) {
            int bin = bin0 + ag * 4 + aa;
            if (bin <= KB4) {
                float dd = bin * DSTEP;
                float env = (bin >= KB4) ? 0.f : 0.5f * (__cosf(dd * (PI_F / CUTOFF)) + 1.f);
                #pragma unroll
                for (int cp = 0; cp < 2; cp++) {
                    unsigned int pk = (unsigned)f2bf(o[aa][2 * cp] * env) |
                                      ((unsigned)f2bf(o[aa][2 * cp + 1] * env) << 16);
                    *(unsigned int*)(tab + base + (size_t)bin * FILTERS + 4 * cq + 2 * cp) = pk;
                }
            }
        }
    } else {
        int eb = bid - TBLK;
        int i0 = eb * 32;
        if (t < 32) s_an[t] = an[i0 + t];
        __syncthreads();
        for (int idx = t; idx < 32 * HIDDEN; idx += 256) {
            int a = idx >> 7, c = idx & 127;
            float v = emb[(size_t)s_an[a] * HIDDEN + c];
            s_row[a][c] = v;
            x[(size_t)(i0 + a) * HIDDEN + c] = v;
        }
        __syncthreads();
        float o[4][4];
        float4 bv = *(const float4*)(d1b + 4 * cq);
        float bva[4] = { bv.x, bv.y, bv.z, bv.w };
        #pragma unroll
        for (int aa = 0; aa < 4; aa++)
            #pragma unroll
            for (int cc = 0; cc < 4; cc++) o[aa][cc] = bva[cc];
        #pragma unroll 4
        for (int h = 0; h < HIDDEN; h += 2) {
            float4 wA = *(const float4*)(d1w + (size_t)h * FILTERS + 4 * cq);
            float4 wB = *(const float4*)(d1w + (size_t)(h + 1) * FILTERS + 4 * cq);
            float wa[4] = { wA.x, wA.y, wA.z, wA.w };
            float wb[4] = { wB.x, wB.y, wB.z, wB.w };
            #pragma unroll
            for (int aa = 0; aa < 4; aa++) {
                float2 hp = *(const float2*)(&s_row[ag * 4 + aa][h]);
                #pragma unroll
                for (int cc = 0; cc < 4; cc++) {
                    o[aa][cc] = fmaf(hp.x, wa[cc], o[aa][cc]);
                    o[aa][cc] = fmaf(hp.y, wb[cc], o[aa][cc]);
                }
            }
        }
        #pragma unroll
        for (int aa = 0; aa < 4; aa++) {
            int i = i0 + ag * 4 + aa;
            #pragma unroll
            for (int cp = 0; cp < 2; cp++) {
                unsigned int pk = (unsigned)f2bf(o[aa][2 * cp]) |
                                  ((unsigned)f2bf(o[aa][2 * cp + 1]) << 16);
                *(unsigned int*)(xj + (size_t)i * FILTERS + 4 * cq + 2 * cp) = pk;
            }
        }
    }
}

// ============ fused 3-layer + pool persistent kernel (256 blocks, 2 atoms each) ============
// Handoff: producers store xj via sc1 (through to coherence point); __syncthreads drains
// vmcnt; done-counter barrier; consumers use PLAIN loads (first touch is post-barrier and
// kernel-launch acquire invalidated all L2s, so no stale line can exist). xj1/xj2 live
// behind 64KB guard gaps so no pre-barrier stream can prefetch them.
__global__ void __launch_bounds__(512) k_layers(const float* __restrict__ pos,
        const unsigned int* __restrict__ tabu, const unsigned int* __restrict__ xj0,
        unsigned int* __restrict__ xj1, unsigned int* __restrict__ xj2,
        const float* __restrict__ x,
        const float* __restrict__ d2w, const float* __restrict__ d2b,
        const float* __restrict__ d1w, const float* __restrict__ d1b,
        const int* __restrict__ batch, float* __restrict__ molsum, int* __restrict__ done,
        const float* __restrict__ ow1, const float* __restrict__ ob1,
        const float* __restrict__ ow2, const float* __restrict__ ob2,
        float* __restrict__ out) {
    int bid = blockIdx.x, t = threadIdx.x;
    int j0a = 2 * bid, j1a = j0a + 1;
    int wv = t >> 6, e = t & 63;
    __shared__ unsigned int s_bin[N_ATOMS];
    __shared__ float s_part[2][8][FILTERS];
    __shared__ float s_red[4][FILTERS];
    __shared__ float s_agg[2][FILTERS];
    __shared__ float s_xn[2][HIDDEN];
    __shared__ int   s_cnt;
    {   // distances once (reused by all 3 layers)
        float px = pos[3*t], py = pos[3*t+1], pz = pos[3*t+2];
        float ax = pos[3*j0a], ay = pos[3*j0a+1], az = pos[3*j0a+2];
        float bx = pos[3*j1a], by = pos[3*j1a+1], bz = pos[3*j1a+2];
        float d0 = sqrtf((px-ax)*(px-ax) + (py-ay)*(py-ay) + (pz-az)*(pz-az));
        float d1 = sqrtf((px-bx)*(px-bx) + (py-by)*(py-by) + (pz-bz)*(pz-bz));
        unsigned int b0 = (t == j0a || d0 >= CUTOFF) ? KB4 : (unsigned)(int)fmaf(d0, DINV, 0.5f);
        unsigned int b1 = (t == j1a || d1 >= CUTOFF) ? KB4 : (unsigned)(int)fmaf(d1, DINV, 0.5f);
        if (b0 > KB4) b0 = KB4;
        if (b1 > KB4) b1 = KB4;
        s_bin[t] = b0 | (b1 << 16);
    }
    int c = t & 127, seg = t >> 7, jj = seg >> 1, sub = seg & 1;
    int jmy = jj ? j1a : j0a;
    float xcur = (sub == 0) ? x[(size_t)jmy * HIDDEN + c] : 0.f;
    __syncthreads();

    for (int l = 0; l < N_LAYERS; l++) {
        const unsigned int* tabl = tabu + (size_t)l * NB4 * 64;
        const unsigned int* xin  = (l == 0) ? xj0 : (l == 1) ? (const unsigned int*)xj1
                                                             : (const unsigned int*)xj2;
        // ---- aggregation: wave wv covers i in [wv*64,+64) for both j's (plain loads) ----
        float a0e = 0.f, a0o = 0.f, a1e = 0.f, a1o = 0.f;
        int i0 = wv * 64;
        for (int ii = 0; ii < 64; ii += 4) {
            #pragma unroll
            for (int r = 0; r < 4; r++) {
                unsigned int pk = s_bin[i0 + ii + r];
                unsigned int bb0 = pk & 0xffffu, bb1 = pk >> 16;
                unsigned int xu = xin[(size_t)(i0 + ii + r) * 64 + e];
                unsigned int f0 = tabl[(size_t)bb0 * 64 + e];
                unsigned int f1 = tabl[(size_t)bb1 * 64 + e];
                float xe = __uint_as_float(xu << 16), xo = __uint_as_float(xu & 0xffff0000u);
                float p0e = __uint_as_float(f0 << 16), p0o = __uint_as_float(f0 & 0xffff0000u);
                float p1e = __uint_as_float(f1 << 16), p1o = __uint_as_float(f1 & 0xffff0000u);
                a0e = fmaf(xe, p0e, a0e);  a0o = fmaf(xo, p0o, a0o);
                a1e = fmaf(xe, p1e, a1e);  a1o = fmaf(xo, p1o, a1o);
            }
        }
        s_part[0][wv][2*e] = a0e;  s_part[0][wv][2*e+1] = a0o;
        s_part[1][wv][2*e] = a1e;  s_part[1][wv][2*e+1] = a1o;
        __syncthreads();
        if (t < 256) {
            int pj = t >> 7, cc = t & 127;
            float s = 0.f;
            #pragma unroll
            for (int w8 = 0; w8 < 8; w8++) s += s_part[pj][w8][cc];
            s_agg[pj][cc] = s;
        }
        __syncthreads();
        // ---- x update ----
        const float* w2 = d2w + (size_t)l * FILTERS * HIDDEN;
        const float* b2 = d2b + (size_t)l * HIDDEN;
        float v = 0.f;
        #pragma unroll 8
        for (int ff = sub * 64; ff < sub * 64 + 64; ff++)
            v = fmaf(s_agg[jj][ff], w2[(size_t)ff * HIDDEN + c], v);
        s_red[seg][c] = v;
        __syncthreads();
        if (sub == 0) {
            xcur = xcur + b2[c] + s_red[jj*2][c] + s_red[jj*2+1][c];
            s_xn[jj][c] = xcur;
        }
        __syncthreads();
        if (l < N_LAYERS - 1) {
            const float* w1n = d1w + (size_t)(l + 1) * HIDDEN * FILTERS;
            const float* b1n = d1b + (size_t)(l + 1) * FILTERS;
            float a2 = 0.f;
            #pragma unroll 8
            for (int hh = sub * 64; hh < sub * 64 + 64; hh++)
                a2 = fmaf(s_xn[jj][hh], w1n[(size_t)hh * FILTERS + c], a2);
            s_red[seg][c] = a2;
            __syncthreads();
            if (sub == 0) s_agg[jj][c] = b1n[c] + s_red[jj*2][c] + s_red[jj*2+1][c];
            __syncthreads();
            unsigned int* xout = (l == 0) ? xj1 : xj2;
            if (t < 128) {
                int row = t >> 6, ee = t & 63;
                unsigned int pk = (unsigned)f2bf(s_agg[row][2*ee]) |
                                  ((unsigned)f2bf(s_agg[row][2*ee+1]) << 16);
                __hip_atomic_store(&xout[(size_t)(j0a + row) * 64 + ee], pk,
                                   __ATOMIC_RELAXED, __HIP_MEMORY_SCOPE_AGENT);
            }
            __syncthreads();                 // vmcnt drained: stores at coherence point
            if (t == 0) {
                atomicAdd(&done[l], 1);
                while (__hip_atomic_load(&done[l], __ATOMIC_RELAXED,
                                         __HIP_MEMORY_SCOPE_AGENT) < NBLK)
                    __builtin_amdgcn_s_sleep(16);
            }
            __syncthreads();
        }
    }
    // ---- pool: accumulate, count, 16 spinner blocks finish ----
    if (sub == 0) atomicAdd(&molsum[(size_t)batch[jmy] * HIDDEN + c], xcur);
    __syncthreads();
    if (t == 0) atomicAdd(&done[2], 1);
    if (bid < N_MOL) {
        int m = bid;
        if (t == 0) {
            while (__hip_atomic_load(&done[2], __ATOMIC_RELAXED,
                                     __HIP_MEMORY_SCOPE_AGENT) < NBLK)
                __builtin_amdgcn_s_sleep(16);
            s_cnt = 0;
        }
        __syncthreads();
        atomicAdd(&s_cnt, (batch[t] == m) ? 1 : 0);
        __syncthreads();
        int cnt = s_cnt;
        if (t < HIDDEN)
            s_xn[0][t] = atomicAdd(&molsum[(size_t)m * HIDDEN + t], 0.f)
                       / (float)(cnt > 0 ? cnt : 1);
        __syncthreads();
        int o = t & 63, sl = t >> 6;
        float a = 0.f;
        #pragma unroll 8
        for (int h = sl * 16; h < sl * 16 + 16; h++)
            a = fmaf(s_xn[0][h], ow1[h * 64 + o], a);
        float* sr = (float*)s_part;
        sr[sl * 64 + o] = a;
        __syncthreads();
        if (t < 64) {
            float vv = ob1[t];
            #pragma unroll
            for (int s8 = 0; s8 < 8; s8++) vv += sr[s8 * 64 + t];
            float hh = vv / (1.f + __expf(-vv));
            float d2 = hh * ow2[t];
            for (int off = 32; off > 0; off >>= 1) d2 += __shfl_down(d2, off, 64);
            if (t == 0) out[m] = d2 + ob2[0];
        }
    }
}

extern "C" void kernel_launch(void* const* d_in, const int* in_sizes, int n_in,
                              void* d_out, int out_size, void* d_ws, size_t ws_size,
                              hipStream_t stream) {
    const int*   an    = (const int*)  d_in[0];
    const float* pos   = (const float*)d_in[1];
    const int*   batch = (const int*)  d_in[2];
    const float* emb   = (const float*)d_in[3];
    const float* fw1   = (const float*)d_in[4];
    const float* fb1   = (const float*)d_in[5];
    const float* fw2   = (const float*)d_in[6];
    const float* fb2   = (const float*)d_in[7];
    const float* d1w   = (const float*)d_in[8];
    const float* d1b   = (const float*)d_in[9];
    const float* d2w   = (const float*)d_in[10];
    const float* d2b   = (const float*)d_in[11];
    const float* ow1   = (const float*)d_in[12];
    const float* ob1   = (const float*)d_in[13];
    const float* ow2   = (const float*)d_in[14];
    const float* ob2   = (const float*)d_in[15];
    float* out = (float*)d_out;

    // layout: x | xj0 | tab | guard | xj1 | guard | xj2 | mols | done
    float*          x    = (float*)d_ws;                               // 256 KB
    unsigned short* xj0  = (unsigned short*)(x + N_ATOMS * HIDDEN);    // 128 KB
    unsigned short* tab  = xj0 + (size_t)N_ATOMS * FILTERS;            // 3.07 MB
    char*           pg   = (char*)(tab + (size_t)N_LAYERS * NB4 * FILTERS) + 65536;
    unsigned int*   xj1  = (unsigned int*)pg;                          // 128 KB
    pg = (char*)(xj1 + (size_t)N_ATOMS * 64) + 65536;
    unsigned int*   xj2  = (unsigned int*)pg;                          // 128 KB
    float*          mols = (float*)(xj2 + (size_t)N_ATOMS * 64);
    int*            done = (int*)(mols + N_MOL * HIDDEN);

    k_front<<<TBLK + EMBB, 256, 0, stream>>>(
        an, emb, d1w, d1b, fw1, fb1, fw2, fb2, x, xj0, tab, mols, done);

    k_layers<<<NBLK, 512, 0, stream>>>(pos, (const unsigned int*)tab,
        (const unsigned int*)xj0, xj1, xj2, x,
        d2w, d2b, d1w, d1b, batch, mols, done, ow1, ob1, ow2, ob2, out);
}

// Round 15
// 59.554 us; speedup vs baseline: 1.2560x; 1.2457x over previous
//
#include <hip/hip_runtime.h>
#include <math.h>

#define N_ATOMS 512
#define N_MOL   16
#define HIDDEN  128
#define FILTERS 128
#define NUM_RBF 50
#define CUTOFF  10.0f
#define N_LAYERS 3

#define KB2    2048                  // nearest-neighbor bins over [0,10]
#define NB2    (KB2 + 1)             // rows 0..2048 (row 2048 ~ zeros via env)
#define TBPL   65                    // table blocks per layer (65*32 >= 2049 bins)
#define TBLK   (N_LAYERS * TBPL)     // 195 table blocks
#define EMBB   16                    // emb blocks, 32 atoms each
#define PI_F   3.14159265358979f
#define DINV   204.8f                // KB2 / CUTOFF
#define DSTEP  (CUTOFF / (float)KB2)
#define TAB_U4 ((NB2 * 64) / 4)      // uint4 count per layer slice (32784)

__device__ __forceinline__ unsigned short f2bf(float v) {
    unsigned u = __float_as_uint(v);
    u += 0x7fffu + ((u >> 16) & 1u);     // round-to-nearest-even
    return (unsigned short)(u >> 16);
}

// ====== front: filter tables as per-block fused GEMM (32 bins/block) ∥ embedding+xj0 ======
__global__ void __launch_bounds__(256) k_front(
        const int* __restrict__ an, const float* __restrict__ emb,
        const float* __restrict__ d1w, const float* __restrict__ d1b,
        const float* __restrict__ fw1, const float* __restrict__ fb1,
        const float* __restrict__ fw2, const float* __restrict__ fb2,
        float* __restrict__ x, unsigned short* __restrict__ xj,
        unsigned short* __restrict__ tab, float* __restrict__ molsum,
        int* __restrict__ done) {
    __shared__ float s_rbf[32][NUM_RBF];
    __shared__ __align__(16) float s_H[32][132];
    __shared__ __align__(16) float s_row[32][HIDDEN];
    __shared__ int   s_an[32];
    int bid = blockIdx.x, t = threadIdx.x;

    if (bid == 0) {
        for (int idx = t; idx < N_MOL * HIDDEN; idx += 256) molsum[idx] = 0.f;
        if (t < 4) done[t] = 0;
    }

    int cq = t & 31, ag = t >> 5;

    if (bid < TBLK) {
        int l = bid / TBPL, bx = bid - l * TBPL;
        int bin0 = bx * 32;
        const float* w1g = fw1 + (size_t)l * NUM_RBF * FILTERS;
        const float* w2g = fw2 + (size_t)l * FILTERS * FILTERS;
        for (int idx = t; idx < 32 * NUM_RBF; idx += 256) {
            int lb = idx / NUM_RBF, r = idx - lb * NUM_RBF;
            float dd = (bin0 + lb) * DSTEP;
            float cr = r * (CUTOFF / (float)(NUM_RBF - 1));
            float xx = dd - cr;
            s_rbf[lb][r] = __expf(-xx * xx * 12.5f);     // 1/(2*w^2), w = 0.2
        }
        __syncthreads();
        {
            float h[4][4];
            float4 bv = *(const float4*)(fb1 + (size_t)l * FILTERS + 4 * cq);
            float bva[4] = { bv.x, bv.y, bv.z, bv.w };
            #pragma unroll
            for (int aa = 0; aa < 4; aa++)
                #pragma unroll
                for (int cc = 0; cc < 4; cc++) h[aa][cc] = bva[cc];
            #pragma unroll 2
            for (int r = 0; r < NUM_RBF; r++) {
                float4 w = *(const float4*)(w1g + (size_t)r * FILTERS + 4 * cq);
                float wa[4] = { w.x, w.y, w.z, w.w };
                #pragma unroll
                for (int aa = 0; aa < 4; aa++) {
                    float rb = s_rbf[ag * 4 + aa][r];
                    #pragma unroll
                    for (int cc = 0; cc < 4; cc++) h[aa][cc] = fmaf(rb, wa[cc], h[aa][cc]);
                }
            }
            __syncthreads();
            #pragma unroll
            for (int aa = 0; aa < 4; aa++) {
                float4 sv;
                sv.x = h[aa][0] / (1.f + __expf(-h[aa][0]));
                sv.y = h[aa][1] / (1.f + __expf(-h[aa][1]));
                sv.z = h[aa][2] / (1.f + __expf(-h[aa][2]));
                sv.w = h[aa][3] / (1.f + __expf(-h[aa][3]));
                *(float4*)(&s_H[ag * 4 + aa][4 * cq]) = sv;
            }
        }
        __syncthreads();
        float o[4][4];
        float4 b2v = *(const float4*)(fb2 + (size_t)l * FILTERS + 4 * cq);
        float b2a[4] = { b2v.x, b2v.y, b2v.z, b2v.w };
        #pragma unroll
        for (int aa = 0; aa < 4; aa++)
            #pragma unroll
            for (int cc = 0; cc < 4; cc++) o[aa][cc] = b2a[cc];
        #pragma unroll 4
        for (int hh = 0; hh < FILTERS; hh += 2) {
            float4 wA = *(const float4*)(w2g + (size_t)hh * FILTERS + 4 * cq);
            float4 wB = *(const float4*)(w2g + (size_t)(hh + 1) * FILTERS + 4 * cq);
            float wa[4] = { wA.x, wA.y, wA.z, wA.w };
            float wb[4] = { wB.x, wB.y, wB.z, wB.w };
            #pragma unroll
            for (int aa = 0; aa < 4; aa++) {
                float2 hp = *(const float2*)(&s_H[ag * 4 + aa][hh]);
                #pragma unroll
                for (int cc = 0; cc < 4; cc++) {
                    o[aa][cc] = fmaf(hp.x, wa[cc], o[aa][cc]);
                    o[aa][cc] = fmaf(hp.y, wb[cc], o[aa][cc]);
                }
            }
        }
        size_t base = (size_t)l * NB2 * FILTERS;
        #pragma unroll
        for (int aa = 0; aa < 4; aa++) {
            int bin = bin0 + ag * 4 + aa;
            if (bin <= KB2) {
                float dd = bin * DSTEP;
                float env = (bin >= KB2) ? 0.f : 0.5f * (__cosf(dd * (PI_F / CUTOFF)) + 1.f);
                #pragma unroll
                for (int cp = 0; cp < 2; cp++) {
                    unsigned int pk = (unsigned)f2bf(o[aa][2 * cp] * env) |
                                      ((unsigned)f2bf(o[aa][2 * cp + 1] * env) << 16);
                    *(unsigned int*)(tab + base + (size_t)bin * FILTERS + 4 * cq + 2 * cp) = pk;
                }
            }
        }
    } else {
        int eb = bid - TBLK;
        int i0 = eb * 32;
        if (t < 32) s_an[t] = an[i0 + t];
        __syncthreads();
        for (int idx = t; idx < 32 * HIDDEN; idx += 256) {
            int a = idx >> 7, c = idx & 127;
            float v = emb[(size_t)s_an[a] * HIDDEN + c];
            s_row[a][c] = v;
            x[(size_t)(i0 + a) * HIDDEN + c] = v;
        }
        __syncthreads();
        float o[4][4];
        float4 bv = *(const float4*)(d1b + 4 * cq);
        float bva[4] = { bv.x, bv.y, bv.z, bv.w };
        #pragma unroll
        for (int aa = 0; aa < 4; aa++)
            #pragma unroll
            for (int cc = 0; cc < 4; cc++) o[aa][cc] = bva[cc];
        #pragma unroll 4
        for (int h = 0; h < HIDDEN; h += 2) {
            float4 wA = *(const float4*)(d1w + (size_t)h * FILTERS + 4 * cq);
            float4 wB = *(const float4*)(d1w + (size_t)(h + 1) * FILTERS + 4 * cq);
            float wa[4] = { wA.x, wA.y, wA.z, wA.w };
            float wb[4] = { wB.x, wB.y, wB.z, wB.w };
            #pragma unroll
            for (int aa = 0; aa < 4; aa++) {
                float2 hp = *(const float2*)(&s_row[ag * 4 + aa][h]);
                #pragma unroll
                for (int cc = 0; cc < 4; cc++) {
                    o[aa][cc] = fmaf(hp.x, wa[cc], o[aa][cc]);
                    o[aa][cc] = fmaf(hp.y, wb[cc], o[aa][cc]);
                }
            }
        }
        #pragma unroll
        for (int aa = 0; aa < 4; aa++) {
            int i = i0 + ag * 4 + aa;
            #pragma unroll
            for (int cp = 0; cp < 2; cp++) {
                unsigned int pk = (unsigned)f2bf(o[aa][2 * cp]) |
                                  ((unsigned)f2bf(o[aa][2 * cp + 1]) << 16);
                *(unsigned int*)(xj + (size_t)i * FILTERS + 4 * cq + 2 * cp) = pk;
            }
        }
    }
}

// ======== layer: 1 j per block, 512 blocks (16 waves/CU); L2-warm pass; last-ticket pool ====
template<int LAST>
__global__ void __launch_bounds__(512) k_layer(const float* __restrict__ pos,
        const unsigned int* __restrict__ tabl, const unsigned int* __restrict__ xj_in,
        float* __restrict__ x, const float* __restrict__ w2, const float* __restrict__ b2,
        const float* __restrict__ w1n, const float* __restrict__ b1n,
        unsigned int* __restrict__ xj_out,
        const int* __restrict__ batch, float* __restrict__ molsum, int* __restrict__ done,
        const float* __restrict__ ow1, const float* __restrict__ ob1,
        const float* __restrict__ ow2, const float* __restrict__ ob2,
        float* __restrict__ out) {
    int j = blockIdx.x, t = threadIdx.x;
    int wv = t >> 6, e = t & 63;
    __shared__ unsigned short s_bin[N_ATOMS];            // 1 KB
    __shared__ float s_part[8][FILTERS];                 // 4 KB
    __shared__ float s_red[4][FILTERS];                  // 2 KB
    __shared__ float s_agg[FILTERS];
    __shared__ float s_xn[HIDDEN];
    __shared__ int   s_tick;
    __shared__ float s_mol[16][HIDDEN];                  // finisher only (8 KB)
    __shared__ float s_h[16][64];                        // finisher only (4 KB)
    __shared__ int   s_c16[16];
    {   // one distance per thread (i = t vs this block's j)
        float px = pos[3*t], py = pos[3*t+1], pz = pos[3*t+2];
        float ax = pos[3*j], ay = pos[3*j+1], az = pos[3*j+2];
        float d = sqrtf((px-ax)*(px-ax) + (py-ay)*(py-ay) + (pz-az)*(pz-az));
        unsigned int b = (t == j || d >= CUTOFF) ? KB2 : (unsigned)(int)fmaf(d, DINV, 0.5f);
        if (b > KB2) b = KB2;
        s_bin[t] = (unsigned short)b;
    }
    int c = t & 127, seg = t >> 7;
    float xold = (seg == 0) ? x[(size_t)j * HIDDEN + c] : 0.f;
    {   // L2 warm: stream this block's tab slice (perf-only; XCD round-robin heuristic)
        const uint4* t4 = (const uint4*)tabl;
        int slice = (j >> 3) & 31;
        int q0 = slice * 1025;
        int qe = q0 + 1025; if (qe > TAB_U4) qe = TAB_U4;
        unsigned int acc = 0;
        for (int q = q0 + t; q < qe; q += 512) {
            uint4 w = t4[q];
            acc ^= w.x ^ w.y ^ w.z ^ w.w;
        }
        asm volatile("" :: "v"(acc));                    // keep warm loads live (rule #17)
    }
    __syncthreads();
    // ---- aggregation: wave wv covers i in [wv*64,+64); lane e owns channels {2e,2e+1} ----
    float ae = 0.f, ao = 0.f;
    int i0 = wv * 64;
    for (int ii = 0; ii < 64; ii += 8) {
        #pragma unroll
        for (int r = 0; r < 8; r++) {
            int bb = s_bin[i0 + ii + r];
            unsigned int xu = xj_in[(size_t)(i0 + ii + r) * 64 + e];
            unsigned int f  = tabl[(size_t)bb * 64 + e];
            float xe = __uint_as_float(xu << 16), xo = __uint_as_float(xu & 0xffff0000u);
            float pe = __uint_as_float(f << 16),  po = __uint_as_float(f & 0xffff0000u);
            ae = fmaf(xe, pe, ae);
            ao = fmaf(xo, po, ao);
        }
    }
    s_part[wv][2*e] = ae;  s_part[wv][2*e+1] = ao;
    __syncthreads();
    if (t < FILTERS) {
        float s = 0.f;
        #pragma unroll
        for (int w8 = 0; w8 < 8; w8++) s += s_part[w8][t];
        s_agg[t] = s;
    }
    __syncthreads();
    // ---- x update: 128-dot split over 4 segments of 32 ----
    float v = 0.f;
    #pragma unroll 8
    for (int ff = seg * 32; ff < seg * 32 + 32; ff++)
        v = fmaf(s_agg[ff], w2[(size_t)ff * HIDDEN + c], v);
    s_red[seg][c] = v;
    __syncthreads();
    float xnew = 0.f;
    if (seg == 0) {
        xnew = xold + b2[c] + s_red[0][c] + s_red[1][c] + s_red[2][c] + s_red[3][c];
        x[(size_t)j * HIDDEN + c] = xnew;
        s_xn[c] = xnew;
    }
    __syncthreads();
    if (!LAST) {
        float a2 = 0.f;
        #pragma unroll 8
        for (int hh = seg * 32; hh < seg * 32 + 32; hh++)
            a2 = fmaf(s_xn[hh], w1n[(size_t)hh * FILTERS + c], a2);
        s_red[seg][c] = a2;
        __syncthreads();
        if (t < 64) {                                    // pack 2 ch per lane
            float v0 = b1n[2*t]   + s_red[0][2*t]   + s_red[1][2*t]   + s_red[2][2*t]   + s_red[3][2*t];
            float v1 = b1n[2*t+1] + s_red[0][2*t+1] + s_red[1][2*t+1] + s_red[2][2*t+1] + s_red[3][2*t+1];
            xj_out[(size_t)j * 64 + t] = (unsigned)f2bf(v0) | ((unsigned)f2bf(v1) << 16);
        }
    } else {
        // ---- pool: molsum adds, then LAST ticket-holder computes all 16 molecules ----
        if (seg == 0) atomicAdd(&molsum[(size_t)batch[j] * HIDDEN + c], xnew);
        __syncthreads();                                 // drains vmcnt (adds at coherence pt)
        if (t == 0) s_tick = atomicAdd(&done[0], 1);
        __syncthreads();
        if (s_tick == (int)gridDim.x - 1) {              // provably last: all adds precede
            if (t < 16) s_c16[t] = 0;
            __syncthreads();
            atomicAdd(&s_c16[batch[t]], 1);              // histogram over 512 atoms
            __syncthreads();
            #pragma unroll
            for (int mo = 0; mo < 4; mo++) {
                int m = mo * 4 + seg;
                float sv = atomicAdd(&molsum[(size_t)m * HIDDEN + c], 0.f);
                int cnt = s_c16[m];
                s_mol[m][c] = sv / (float)(cnt > 0 ? cnt : 1);
            }
            __syncthreads();
            #pragma unroll
            for (int rr = 0; rr < 2; rr++) {             // 1024 MLP1 outputs, 2/thread
                int o = t + rr * 512;
                int m = o >> 6, k = o & 63;
                float a = ob1[k];
                #pragma unroll 8
                for (int h = 0; h < HIDDEN; h++) a = fmaf(s_mol[m][h], ow1[h * 64 + k], a);
                s_h[m][k] = a / (1.f + __expf(-a));      // silu
            }
            __syncthreads();
            if (t < N_MOL) {
                float a = ob2[0];
                #pragma unroll 8
                for (int h = 0; h < 64; h++) a = fmaf(s_h[t][h], ow2[h], a);
                out[t] = a;
            }
        }
    }
}

extern "C" void kernel_launch(void* const* d_in, const int* in_sizes, int n_in,
                              void* d_out, int out_size, void* d_ws, size_t ws_size,
                              hipStream_t stream) {
    const int*   an    = (const int*)  d_in[0];
    const float* pos   = (const float*)d_in[1];
    const int*   batch = (const int*)  d_in[2];
    const float* emb   = (const float*)d_in[3];
    const float* fw1   = (const float*)d_in[4];
    const float* fb1   = (const float*)d_in[5];
    const float* fw2   = (const float*)d_in[6];
    const float* fb2   = (const float*)d_in[7];
    const float* d1w   = (const float*)d_in[8];
    const float* d1b   = (const float*)d_in[9];
    const float* d2w   = (const float*)d_in[10];
    const float* d2b   = (const float*)d_in[11];
    const float* ow1   = (const float*)d_in[12];
    const float* ob1   = (const float*)d_in[13];
    const float* ow2   = (const float*)d_in[14];
    const float* ob2   = (const float*)d_in[15];
    float* out = (float*)d_out;

    float*          x    = (float*)d_ws;                               // 256 KB
    unsigned int*   xj0  = (unsigned int*)(x + N_ATOMS * HIDDEN);      // 128 KB
    unsigned int*   xj1  = xj0 + (size_t)N_ATOMS * 64;                 // 128 KB
    unsigned int*   xj2  = xj1 + (size_t)N_ATOMS * 64;                 // 128 KB
    unsigned short* tab  = (unsigned short*)(xj2 + (size_t)N_ATOMS * 64);  // 1.54 MB
    float*          mols = (float*)(tab + (size_t)N_LAYERS * NB2 * FILTERS);
    int*            done = (int*)(mols + N_MOL * HIDDEN);

    k_front<<<TBLK + EMBB, 256, 0, stream>>>(
        an, emb, d1w, d1b, fw1, fb1, fw2, fb2, x, (unsigned short*)xj0, tab, mols, done);

    const unsigned int* t0 = (const unsigned int*)(tab + (size_t)0 * NB2 * FILTERS);
    const unsigned int* t1 = (const unsigned int*)(tab + (size_t)1 * NB2 * FILTERS);
    const unsigned int* t2 = (const unsigned int*)(tab + (size_t)2 * NB2 * FILTERS);

    k_layer<0><<<N_ATOMS, 512, 0, stream>>>(pos, t0, xj0, x,
        d2w + (size_t)0*FILTERS*HIDDEN, d2b + (size_t)0*HIDDEN,
        d1w + (size_t)1*HIDDEN*FILTERS, d1b + (size_t)1*FILTERS, xj1,
        batch, mols, done, ow1, ob1, ow2, ob2, out);
    k_layer<0><<<N_ATOMS, 512, 0, stream>>>(pos, t1, xj1, x,
        d2w + (size_t)1*FILTERS*HIDDEN, d2b + (size_t)1*HIDDEN,
        d1w + (size_t)2*HIDDEN*FILTERS, d1b + (size_t)2*FILTERS, xj2,
        batch, mols, done, ow1, ob1, ow2, ob2, out);
    k_layer<1><<<N_ATOMS, 512, 0, stream>>>(pos, t2, xj2, x,
        d2w + (size_t)2*FILTERS*HIDDEN, d2b + (size_t)2*HIDDEN,
        d1w, d1b, xj0,
        batch, mols, done, ow1, ob1, ow2, ob2, out);
}